// Round 2
// baseline (859.565 us; speedup 1.0000x reference)
//
#include <hip/hip_runtime.h>
#include <hip/hip_bf16.h>
#include <math.h>

// Problem constants
#define BSZ     2
#define LLEN    1024
#define DM      1024
#define DI      2048
#define DS      16
#define DTR     128
#define NXP     160          // DTR + 2*DS
#define MROWS   (BSZ*LLEN)   // 2048

// ---------------------------------------------------------------------------
// Kernel 1: LayerNorm  (2048 rows of 1024)
// ---------------------------------------------------------------------------
__global__ __launch_bounds__(256) void ln_kernel(
    const float* __restrict__ x, const float* __restrict__ w,
    const float* __restrict__ b, float* __restrict__ h)
{
    const int r = blockIdx.x;            // 0..2047
    const int tid = threadIdx.x;         // 0..255
    const float4 v = ((const float4*)(x + (size_t)r * DM))[tid];
    float s  = v.x + v.y + v.z + v.w;
    float q  = v.x*v.x + v.y*v.y + v.z*v.z + v.w*v.w;
    #pragma unroll
    for (int o = 32; o > 0; o >>= 1) {
        s += __shfl_down(s, o);
        q += __shfl_down(q, o);
    }
    __shared__ float ss[4], sq[4];
    if ((tid & 63) == 0) { ss[tid >> 6] = s; sq[tid >> 6] = q; }
    __syncthreads();
    s = ss[0] + ss[1] + ss[2] + ss[3];
    q = sq[0] + sq[1] + sq[2] + sq[3];
    const float mu  = s * (1.0f / DM);
    const float var = q * (1.0f / DM) - mu * mu;
    const float rs  = rsqrtf(var + 1e-5f);
    const float4 wv = ((const float4*)w)[tid];
    const float4 bv = ((const float4*)b)[tid];
    float4 o;
    o.x = (v.x - mu) * rs * wv.x + bv.x;
    o.y = (v.y - mu) * rs * wv.y + bv.y;
    o.z = (v.z - mu) * rs * wv.z + bv.z;
    o.w = (v.w - mu) * rs * wv.w + bv.w;
    ((float4*)(h + (size_t)r * DM))[tid] = o;
}

// ---------------------------------------------------------------------------
// Kernel 2: generic fp32 tiled GEMM  C[M,N] = A[M,K] @ B[K,N]  (+epilogue)
// EPI: 0 = none, 1 = softplus(acc + bias[n]), 2 = acc + resid[m*ldc+n]
// Tiles: 64x64, BK=16, 256 threads, 4x4 per thread.
// ---------------------------------------------------------------------------
template<int EPI>
__global__ __launch_bounds__(256) void gemm_f32(
    const float* __restrict__ A, int lda,
    const float* __restrict__ Bw, int ldb,
    float* __restrict__ C, int ldc,
    int M, int N, int Kdim,
    const float* __restrict__ bias,
    const float* __restrict__ resid)
{
    __shared__ float As[16][64];
    __shared__ float Bs[16][64];
    const int tid = threadIdx.x;
    const int m0 = blockIdx.y * 64;
    const int n0 = blockIdx.x * 64;
    const int tm = tid >> 4;     // 0..15
    const int tn = tid & 15;     // 0..15

    float acc[4][4] = {};

    const int mA  = tid >> 2;           // 0..63
    const int kkA = (tid & 3) << 2;     // 0,4,8,12
    const int kB  = tid >> 4;           // 0..15
    const int nnB = (tid & 15) << 2;    // 0..60

    for (int kt = 0; kt < Kdim; kt += 16) {
        // stage A (transposed) and B
        const float4 av = *(const float4*)&A[(size_t)(m0 + mA) * lda + kt + kkA];
        As[kkA + 0][mA] = av.x;
        As[kkA + 1][mA] = av.y;
        As[kkA + 2][mA] = av.z;
        As[kkA + 3][mA] = av.w;
        float4 bv = make_float4(0.f, 0.f, 0.f, 0.f);
        if (n0 + nnB < N)
            bv = *(const float4*)&Bw[(size_t)(kt + kB) * ldb + n0 + nnB];
        *(float4*)&Bs[kB][nnB] = bv;
        __syncthreads();

        #pragma unroll
        for (int k = 0; k < 16; ++k) {
            const float4 a = *(const float4*)&As[k][tm << 2];
            const float4 b = *(const float4*)&Bs[k][tn << 2];
            const float ar[4] = {a.x, a.y, a.z, a.w};
            const float br[4] = {b.x, b.y, b.z, b.w};
            #pragma unroll
            for (int i = 0; i < 4; ++i)
                #pragma unroll
                for (int j = 0; j < 4; ++j)
                    acc[i][j] = fmaf(ar[i], br[j], acc[i][j]);
        }
        __syncthreads();
    }

    const int col0 = n0 + (tn << 2);
    if (col0 >= N) return;
    const int row0 = m0 + (tm << 2);
    #pragma unroll
    for (int i = 0; i < 4; ++i) {
        float v[4] = {acc[i][0], acc[i][1], acc[i][2], acc[i][3]};
        if (EPI == 1) {
            #pragma unroll
            for (int j = 0; j < 4; ++j) {
                float t = v[j] + bias[col0 + j];
                v[j] = (t > 20.f) ? t : log1pf(__expf(t));
            }
        } else if (EPI == 2) {
            const float4 rv = *(const float4*)&resid[(size_t)(row0 + i) * ldc + col0];
            v[0] += rv.x; v[1] += rv.y; v[2] += rv.z; v[3] += rv.w;
        }
        float4 o = {v[0], v[1], v[2], v[3]};
        *(float4*)&C[(size_t)(row0 + i) * ldc + col0] = o;
    }
}

// ---------------------------------------------------------------------------
// Kernel 3: causal depthwise conv (K=4) + SiLU
// xr layout: (b,l,4096); xs_raw = cols [0,2048)
// ---------------------------------------------------------------------------
__global__ __launch_bounds__(256) void conv_silu(
    const float* __restrict__ xr, const float* __restrict__ cw,
    const float* __restrict__ cb, float* __restrict__ xs)
{
    const int idx = blockIdx.x * 256 + threadIdx.x;   // over 2*1024*2048
    const int d = idx & (DI - 1);
    const int t = (idx >> 11) & (LLEN - 1);
    const int b = idx >> 21;
    const float4 wv = ((const float4*)cw)[d];
    const float w[4] = {wv.x, wv.y, wv.z, wv.w};
    float acc = cb[d];
    #pragma unroll
    for (int k = 0; k < 4; ++k) {
        const int tt = t + k - 3;
        if (tt >= 0)
            acc = fmaf(w[k], xr[((size_t)(b * LLEN + tt) << 12) + d], acc);
    }
    const float sig = 1.f / (1.f + __expf(-acc));
    xs[idx] = acc * sig;
}

// ---------------------------------------------------------------------------
// Kernel 6: selective scan.
// 256 blocks; block -> (b, 16 channels). 16 lanes per channel (one per state).
// Writes y (incl. +u*D and *silu(res)) in-place over xs.
// ---------------------------------------------------------------------------
__global__ __launch_bounds__(256) void scan_kernel(
    const float* __restrict__ delta,  // (2048, 2048)
    float* __restrict__ xs,           // u in, y out (2048, 2048)
    const float* __restrict__ xp,     // (2048, 160): B at 128, C at 144
    const float* __restrict__ xr,     // res at col 2048 of 4096
    const float* __restrict__ A_log,  // (2048, 16)
    const float* __restrict__ Dp)     // (2048,)
{
    const int bi  = blockIdx.x;           // 0..255
    const int b   = bi >> 7;              // 0..1
    const int d0  = (bi & 127) << 4;      // channel base
    const int tid = threadIdx.x;
    const int c   = tid >> 4;             // local channel 0..15
    const int n   = tid & 15;             // state index
    const int d   = d0 + c;

    const float aL = -__expf(A_log[(size_t)d * DS + n]) * 1.44269504088896f;
    const float Dd = Dp[d];

    __shared__ float sDelta[64][16], sU[64][16], sB[64][16], sC[64][16],
                     sRes[64][16], sY[64][16];

    float h = 0.f;
    for (int ch = 0; ch < LLEN / 64; ++ch) {
        const int t0 = ch * 64;
        #pragma unroll
        for (int q = 0; q < 4; ++q) {
            const int idx = q * 256 + tid;       // 0..1023
            const int i = idx >> 4, j = idx & 15;
            const size_t row = (size_t)(b * LLEN + t0 + i);
            sDelta[i][j] = delta[row * DI + d0 + j];
            sU[i][j]     = xs[row * DI + d0 + j];
            sB[i][j]     = xp[row * NXP + DTR + j];
            sC[i][j]     = xp[row * NXP + DTR + DS + j];
            sRes[i][j]   = xr[(row << 12) + DI + d0 + j];
        }
        __syncthreads();

        for (int i = 0; i < 64; ++i) {
            const float dlt = sDelta[i][c];
            const float u   = sU[i][c];
            const float dA  = exp2f(dlt * aL);
            const float dBu = dlt * u * sB[i][n];
            h = fmaf(dA, h, dBu);
            float p = h * sC[i][n];
            p += __shfl_xor(p, 1);
            p += __shfl_xor(p, 2);
            p += __shfl_xor(p, 4);
            p += __shfl_xor(p, 8);
            if (n == 0) {
                const float y = p + Dd * u;
                const float r = sRes[i][c];
                const float yf = y * (r / (1.f + __expf(-r)));
                sY[i][c] = yf;
            }
        }
        __syncthreads();

        #pragma unroll
        for (int q = 0; q < 4; ++q) {
            const int idx = q * 256 + tid;
            const int i = idx >> 4, j = idx & 15;
            xs[(size_t)(b * LLEN + t0 + i) * DI + d0 + j] = sY[i][j];
        }
        __syncthreads();
    }
}

// ---------------------------------------------------------------------------
extern "C" void kernel_launch(void* const* d_in, const int* in_sizes, int n_in,
                              void* d_out, int out_size, void* d_ws, size_t ws_size,
                              hipStream_t stream)
{
    (void)in_sizes; (void)n_in; (void)out_size; (void)ws_size;
    const float* x         = (const float*)d_in[0];
    const float* norm_w    = (const float*)d_in[1];
    const float* norm_b    = (const float*)d_in[2];
    const float* in_proj_w = (const float*)d_in[3];   // (1024, 4096)
    const float* conv_w    = (const float*)d_in[4];   // (2048, 4)
    const float* conv_b    = (const float*)d_in[5];
    const float* x_proj_w  = (const float*)d_in[6];   // (2048, 160)
    const float* dt_proj_w = (const float*)d_in[7];   // (128, 2048)
    const float* dt_proj_b = (const float*)d_in[8];
    const float* A_log     = (const float*)d_in[9];   // (2048, 16)
    const float* D_param   = (const float*)d_in[10];
    const float* out_proj_w= (const float*)d_in[11];  // (2048, 1024)
    float* out = (float*)d_out;

    char* ws = (char*)d_ws;
    float* xr    = (float*)(ws);                       // 2048x4096 (32 MB)
    float* h     = (float*)(ws + 33554432);            // 2048x1024 (8 MB)
    float* xs    = (float*)(ws + 41943040);            // 2048x2048 (16 MB)
    float* xp    = (float*)(ws + 58720256);            // 2048x160
    float* delta = (float*)(ws + 60817408);            // 2048x2048 (16 MB)

    // 1. LayerNorm
    ln_kernel<<<MROWS, 256, 0, stream>>>(x, norm_w, norm_b, h);

    // 2. in_proj: (2048,1024)@(1024,4096) -> xr
    gemm_f32<0><<<dim3(4096 / 64, MROWS / 64), 256, 0, stream>>>(
        h, DM, in_proj_w, 2 * DI, xr, 2 * DI, MROWS, 2 * DI, DM, nullptr, nullptr);

    // 3. conv + silu -> xs
    conv_silu<<<(BSZ * LLEN * DI) / 256, 256, 0, stream>>>(xr, conv_w, conv_b, xs);

    // 4. x_proj: (2048,2048)@(2048,160) -> xp
    gemm_f32<0><<<dim3((NXP + 63) / 64, MROWS / 64), 256, 0, stream>>>(
        xs, DI, x_proj_w, NXP, xp, NXP, MROWS, NXP, DI, nullptr, nullptr);

    // 5. dt_proj + softplus: dr = xp[:, :128]; (2048,128)@(128,2048) -> delta
    gemm_f32<1><<<dim3(DI / 64, MROWS / 64), 256, 0, stream>>>(
        xp, NXP, dt_proj_w, DI, delta, DI, MROWS, DI, DTR, dt_proj_b, nullptr);

    // 6. selective scan (+ u*D, * silu(res)) -> y in-place over xs
    scan_kernel<<<256, 256, 0, stream>>>(delta, xs, xp, xr, A_log, D_param);

    // 7. out_proj + residual: (2048,2048)@(2048,1024) + x -> out
    //    FIX: (M,N,K) was (2048,2048,1024) — K truncated to half. Correct: N=DM, K=DI.
    gemm_f32<2><<<dim3(DM / 64, MROWS / 64), 256, 0, stream>>>(
        xs, DI, out_proj_w, DM, out, DM, MROWS, DM, DI, nullptr, x);
}

// Round 3
// 361.071 us; speedup vs baseline: 2.3806x; 2.3806x over previous
//
#include <hip/hip_runtime.h>
#include <hip/hip_bf16.h>
#include <math.h>

// Problem constants
#define BSZ     2
#define LLEN    1024
#define DM      1024
#define DI      2048
#define DS      16
#define DTR     128
#define NXP     160          // DTR + 2*DS
#define MROWS   (BSZ*LLEN)   // 2048
#define NCH     16           // scan chunks
#define CHL     (LLEN/NCH)   // 64 steps per chunk

typedef short  bf16x8 __attribute__((ext_vector_type(8)));   // 8 bf16 (4 VGPRs)
typedef float  f32x4  __attribute__((ext_vector_type(4)));

__device__ __forceinline__ unsigned short f2bf(float f) {
    unsigned int u = __float_as_uint(f);
    return (unsigned short)((u + 0x7FFFu + ((u >> 16) & 1u)) >> 16);   // RNE
}

// ---------------------------------------------------------------------------
// Kernel 1: LayerNorm -> bf16 output (2048 rows of 1024)
// ---------------------------------------------------------------------------
__global__ __launch_bounds__(256) void ln_bf16(
    const float* __restrict__ x, const float* __restrict__ w,
    const float* __restrict__ b, unsigned short* __restrict__ hb)
{
    const int r = blockIdx.x;
    const int tid = threadIdx.x;
    const float4 v = ((const float4*)(x + (size_t)r * DM))[tid];
    float s  = v.x + v.y + v.z + v.w;
    float q  = v.x*v.x + v.y*v.y + v.z*v.z + v.w*v.w;
    #pragma unroll
    for (int o = 32; o > 0; o >>= 1) {
        s += __shfl_down(s, o);
        q += __shfl_down(q, o);
    }
    __shared__ float ss[4], sq[4];
    if ((tid & 63) == 0) { ss[tid >> 6] = s; sq[tid >> 6] = q; }
    __syncthreads();
    s = ss[0] + ss[1] + ss[2] + ss[3];
    q = sq[0] + sq[1] + sq[2] + sq[3];
    const float mu  = s * (1.0f / DM);
    const float var = q * (1.0f / DM) - mu * mu;
    const float rs  = rsqrtf(var + 1e-5f);
    const float4 wv = ((const float4*)w)[tid];
    const float4 bv = ((const float4*)b)[tid];
    ushort4 ob;
    ob.x = f2bf((v.x - mu) * rs * wv.x + bv.x);
    ob.y = f2bf((v.y - mu) * rs * wv.y + bv.y);
    ob.z = f2bf((v.z - mu) * rs * wv.z + bv.z);
    ob.w = f2bf((v.w - mu) * rs * wv.w + bv.w);
    *(ushort4*)&hb[(size_t)r * DM + (tid << 2)] = ob;
}

// ---------------------------------------------------------------------------
// cast fp32 [K][N] -> bf16 [N][K] (transpose) via 64x64 LDS tile
// ---------------------------------------------------------------------------
__global__ __launch_bounds__(256) void cast_transpose(
    const float* __restrict__ src, unsigned short* __restrict__ dst,
    int K, int N)
{
    __shared__ unsigned short t[64][68];
    const int tid = threadIdx.x;
    const int k0 = blockIdx.y * 64, n0 = blockIdx.x * 64;
    #pragma unroll
    for (int q = 0; q < 4; ++q) {
        int idx = q * 256 + tid;
        int r = idx >> 4, c = (idx & 15) * 4;
        float4 v = *(const float4*)&src[(size_t)(k0 + r) * N + n0 + c];
        t[r][c]   = f2bf(v.x); t[r][c+1] = f2bf(v.y);
        t[r][c+2] = f2bf(v.z); t[r][c+3] = f2bf(v.w);
    }
    __syncthreads();
    #pragma unroll
    for (int q = 0; q < 4; ++q) {
        int idx = q * 256 + tid;
        int r = idx >> 4, c = (idx & 15) * 4;    // r: n-row, c: k-col
        ushort4 o;
        o.x = t[c][r]; o.y = t[c+1][r]; o.z = t[c+2][r]; o.w = t[c+3][r];
        *(ushort4*)&dst[(size_t)(n0 + r) * K + k0 + c] = o;
    }
}

// ---------------------------------------------------------------------------
// cast fp32 -> bf16 (same layout)
// ---------------------------------------------------------------------------
__global__ __launch_bounds__(256) void cast_bf16(
    const float* __restrict__ src, unsigned short* __restrict__ dst, int n)
{
    int i = (blockIdx.x * 256 + threadIdx.x) * 4;
    if (i < n) {
        float4 v = *(const float4*)&src[i];
        ushort4 o = { f2bf(v.x), f2bf(v.y), f2bf(v.z), f2bf(v.w) };
        *(ushort4*)&dst[i] = o;
    }
}

// ---------------------------------------------------------------------------
// bf16 MFMA GEMM: C[M,N](fp32) = A[M,K](bf16) @ Bt[N,K](bf16)^T
// Tile BM x BN, BK=64, 256 threads = 4 waves (2x2), 16x16x32 MFMA.
// EPI: 0 = none, 2 = + resid[row*N+col]
// ---------------------------------------------------------------------------
template<int BM, int BN, int EPI>
__global__ __launch_bounds__(256) void gemm_bf16(
    const unsigned short* __restrict__ A,
    const unsigned short* __restrict__ Bt,
    float* __restrict__ C, int M, int N, int K,
    const float* __restrict__ resid)
{
    constexpr int LDT = 72;                 // padded (2-way conflicts only)
    __shared__ unsigned short As[BM][LDT];
    __shared__ unsigned short Bs[BN][LDT];
    const int tid  = threadIdx.x;
    const int m0   = blockIdx.y * BM;
    const int n0   = blockIdx.x * BN;
    const int wave = tid >> 6;
    const int lane = tid & 63;
    const int wr   = (wave >> 1) * (BM / 2);
    const int wc   = (wave & 1) * (BN / 2);
    constexpr int FM = BM / 32;             // frags per wave (M)
    constexpr int FN = BN / 32;             // frags per wave (N)
    const int l15 = lane & 15;
    const int kg  = lane >> 4;              // 0..3

    f32x4 acc[FM][FN] = {};

    for (int kt = 0; kt < K; kt += 64) {
        __syncthreads();
        #pragma unroll
        for (int q = 0; q < BM / 32; ++q) {
            int idx = q * 256 + tid;
            int r = idx >> 3, c = (idx & 7) * 8;
            *(uint4*)&As[r][c] = *(const uint4*)&A[(size_t)(m0 + r) * K + kt + c];
        }
        #pragma unroll
        for (int q = 0; q < BN / 32; ++q) {
            int idx = q * 256 + tid;
            int r = idx >> 3, c = (idx & 7) * 8;
            *(uint4*)&Bs[r][c] = *(const uint4*)&Bt[(size_t)(n0 + r) * K + kt + c];
        }
        __syncthreads();
        #pragma unroll
        for (int ks = 0; ks < 2; ++ks) {
            bf16x8 af[FM], bfr[FN];
            #pragma unroll
            for (int i = 0; i < FM; ++i)
                af[i] = *(const bf16x8*)&As[wr + i * 16 + l15][ks * 32 + kg * 8];
            #pragma unroll
            for (int j = 0; j < FN; ++j)
                bfr[j] = *(const bf16x8*)&Bs[wc + j * 16 + l15][ks * 32 + kg * 8];
            #pragma unroll
            for (int i = 0; i < FM; ++i)
                #pragma unroll
                for (int j = 0; j < FN; ++j)
                    acc[i][j] = __builtin_amdgcn_mfma_f32_16x16x32_bf16(
                        af[i], bfr[j], acc[i][j], 0, 0, 0);
        }
    }
    // C/D layout: col = lane&15, row = (lane>>4)*4 + reg   [m89-verified]
    #pragma unroll
    for (int i = 0; i < FM; ++i) {
        #pragma unroll
        for (int j = 0; j < FN; ++j) {
            const int row = m0 + wr + i * 16 + kg * 4;
            const int col = n0 + wc + j * 16 + l15;
            #pragma unroll
            for (int r = 0; r < 4; ++r) {
                float v = acc[i][j][r];
                if (EPI == 2) v += resid[(size_t)(row + r) * N + col];
                C[(size_t)(row + r) * N + col] = v;
            }
        }
    }
}

// ---------------------------------------------------------------------------
// fp32 tiled GEMM (kept for x_proj / dt_proj)
// EPI: 0 = none, 1 = softplus(acc + bias[n])
// ---------------------------------------------------------------------------
template<int EPI>
__global__ __launch_bounds__(256) void gemm_f32(
    const float* __restrict__ A, int lda,
    const float* __restrict__ Bw, int ldb,
    float* __restrict__ C, int ldc,
    int M, int N, int Kdim,
    const float* __restrict__ bias)
{
    __shared__ float As[16][64];
    __shared__ float Bs[16][64];
    const int tid = threadIdx.x;
    const int m0 = blockIdx.y * 64;
    const int n0 = blockIdx.x * 64;
    const int tm = tid >> 4;
    const int tn = tid & 15;

    float acc[4][4] = {};

    const int mA  = tid >> 2;
    const int kkA = (tid & 3) << 2;
    const int kB  = tid >> 4;
    const int nnB = (tid & 15) << 2;

    for (int kt = 0; kt < Kdim; kt += 16) {
        const float4 av = *(const float4*)&A[(size_t)(m0 + mA) * lda + kt + kkA];
        As[kkA + 0][mA] = av.x;
        As[kkA + 1][mA] = av.y;
        As[kkA + 2][mA] = av.z;
        As[kkA + 3][mA] = av.w;
        float4 bv = make_float4(0.f, 0.f, 0.f, 0.f);
        if (n0 + nnB < N)
            bv = *(const float4*)&Bw[(size_t)(kt + kB) * ldb + n0 + nnB];
        *(float4*)&Bs[kB][nnB] = bv;
        __syncthreads();

        #pragma unroll
        for (int k = 0; k < 16; ++k) {
            const float4 a = *(const float4*)&As[k][tm << 2];
            const float4 b = *(const float4*)&Bs[k][tn << 2];
            const float ar[4] = {a.x, a.y, a.z, a.w};
            const float br[4] = {b.x, b.y, b.z, b.w};
            #pragma unroll
            for (int i = 0; i < 4; ++i)
                #pragma unroll
                for (int j = 0; j < 4; ++j)
                    acc[i][j] = fmaf(ar[i], br[j], acc[i][j]);
        }
        __syncthreads();
    }

    const int col0 = n0 + (tn << 2);
    if (col0 >= N) return;
    const int row0 = m0 + (tm << 2);
    #pragma unroll
    for (int i = 0; i < 4; ++i) {
        float v[4] = {acc[i][0], acc[i][1], acc[i][2], acc[i][3]};
        if (EPI == 1) {
            #pragma unroll
            for (int j = 0; j < 4; ++j) {
                float t = v[j] + bias[col0 + j];
                v[j] = (t > 20.f) ? t : log1pf(__expf(t));
            }
        }
        float4 o = {v[0], v[1], v[2], v[3]};
        *(float4*)&C[(size_t)(row0 + i) * ldc + col0] = o;
    }
}

// ---------------------------------------------------------------------------
// causal depthwise conv (K=4) + SiLU
// ---------------------------------------------------------------------------
__global__ __launch_bounds__(256) void conv_silu(
    const float* __restrict__ xr, const float* __restrict__ cw,
    const float* __restrict__ cb, float* __restrict__ xs)
{
    const int idx = blockIdx.x * 256 + threadIdx.x;
    const int d = idx & (DI - 1);
    const int t = (idx >> 11) & (LLEN - 1);
    const int b = idx >> 21;
    const float4 wv = ((const float4*)cw)[d];
    const float w[4] = {wv.x, wv.y, wv.z, wv.w};
    float acc = cb[d];
    #pragma unroll
    for (int k = 0; k < 4; ++k) {
        const int tt = t + k - 3;
        if (tt >= 0)
            acc = fmaf(w[k], xr[((size_t)(b * LLEN + tt) << 12) + d], acc);
    }
    const float sig = 1.f / (1.f + __expf(-acc));
    xs[idx] = acc * sig;
}

// ---------------------------------------------------------------------------
// Scan pass A: per (b,d,chunk): P = prod dA, S = chunk-local final h
// One thread per (d,chunk) holds 16 states in registers.
// P/S layout: [chunk][b][d][n]
// ---------------------------------------------------------------------------
__global__ __launch_bounds__(256) void scan_ps(
    const float* __restrict__ delta, const float* __restrict__ xs,
    const float* __restrict__ xp, const float* __restrict__ A_log,
    float* __restrict__ P, float* __restrict__ S)
{
    const int blk  = blockIdx.x;
    const int dgrp = blk & 7;
    const int j    = (blk >> 3) & (NCH - 1);
    const int b    = blk >> 7;
    const int d    = dgrp * 256 + threadIdx.x;
    float aL[DS], h[DS], Pp[DS];
    #pragma unroll
    for (int n = 0; n < DS; ++n) {
        aL[n] = -__expf(A_log[d * DS + n]) * 1.44269504088896f;
        h[n] = 0.f; Pp[n] = 1.f;
    }
    const int t0 = j * CHL;
    for (int t = t0; t < t0 + CHL; ++t) {
        const size_t row = (size_t)(b * LLEN + t);
        const float dlt = delta[row * DI + d];
        const float du  = dlt * xs[row * DI + d];
        const float* Bp = &xp[row * NXP + DTR];
        #pragma unroll
        for (int n = 0; n < DS; ++n) {
            const float dA = exp2f(dlt * aL[n]);
            h[n] = fmaf(dA, h[n], du * Bp[n]);
            Pp[n] *= dA;
        }
    }
    float* Po = &P[(((size_t)j * BSZ + b) * DI + d) * DS];
    float* So = &S[(((size_t)j * BSZ + b) * DI + d) * DS];
    #pragma unroll
    for (int n = 0; n < DS; ++n) { Po[n] = Pp[n]; So[n] = h[n]; }
}

// ---------------------------------------------------------------------------
// Scan pass B: sequential inter-chunk fix-up; writes H0 over P in-place.
// ---------------------------------------------------------------------------
__global__ __launch_bounds__(256) void scan_fix(
    float* __restrict__ P, const float* __restrict__ S)
{
    const int c = blockIdx.x * 256 + threadIdx.x;   // (b,d,n) chain
    const int stride = BSZ * DI * DS;
    float h = 0.f;
    #pragma unroll
    for (int j = 0; j < NCH; ++j) {
        const float Pj = P[(size_t)j * stride + c];
        const float Sj = S[(size_t)j * stride + c];
        P[(size_t)j * stride + c] = h;              // H0 for chunk j
        h = fmaf(Pj, h, Sj);
    }
}

// ---------------------------------------------------------------------------
// Scan pass C: re-run chunk with correct h0; y = (sum h*C + D*u) * silu(res)
// writes y fp32 in-place over xs.
// ---------------------------------------------------------------------------
__global__ __launch_bounds__(256) void scan_y(
    const float* __restrict__ delta, float* __restrict__ xs,
    const float* __restrict__ xp, const float* __restrict__ xr,
    const float* __restrict__ A_log, const float* __restrict__ Dp,
    const float* __restrict__ H0)
{
    const int blk  = blockIdx.x;
    const int dgrp = blk & 7;
    const int j    = (blk >> 3) & (NCH - 1);
    const int b    = blk >> 7;
    const int d    = dgrp * 256 + threadIdx.x;
    float aL[DS], h[DS];
    const float* H = &H0[(((size_t)j * BSZ + b) * DI + d) * DS];
    #pragma unroll
    for (int n = 0; n < DS; ++n) {
        aL[n] = -__expf(A_log[d * DS + n]) * 1.44269504088896f;
        h[n] = H[n];
    }
    const float Dd = Dp[d];
    const int t0 = j * CHL;
    for (int t = t0; t < t0 + CHL; ++t) {
        const size_t row = (size_t)(b * LLEN + t);
        const float dlt = delta[row * DI + d];
        const float u   = xs[row * DI + d];
        const float du  = dlt * u;
        const float* Bp = &xp[row * NXP + DTR];
        const float* Cp = Bp + DS;
        float y = Dd * u;
        #pragma unroll
        for (int n = 0; n < DS; ++n) {
            const float dA = exp2f(dlt * aL[n]);
            h[n] = fmaf(dA, h[n], du * Bp[n]);
            y = fmaf(h[n], Cp[n], y);
        }
        const float r = xr[(row << 12) + DI + d];
        xs[row * DI + d] = y * (r / (1.f + __expf(-r)));
    }
}

// ---------------------------------------------------------------------------
extern "C" void kernel_launch(void* const* d_in, const int* in_sizes, int n_in,
                              void* d_out, int out_size, void* d_ws, size_t ws_size,
                              hipStream_t stream)
{
    (void)in_sizes; (void)n_in; (void)out_size; (void)ws_size;
    const float* x         = (const float*)d_in[0];
    const float* norm_w    = (const float*)d_in[1];
    const float* norm_b    = (const float*)d_in[2];
    const float* in_proj_w = (const float*)d_in[3];   // (1024, 4096)
    const float* conv_w    = (const float*)d_in[4];
    const float* conv_b    = (const float*)d_in[5];
    const float* x_proj_w  = (const float*)d_in[6];   // (2048, 160)
    const float* dt_proj_w = (const float*)d_in[7];   // (128, 2048)
    const float* dt_proj_b = (const float*)d_in[8];
    const float* A_log     = (const float*)d_in[9];
    const float* D_param   = (const float*)d_in[10];
    const float* out_proj_w= (const float*)d_in[11];  // (2048, 1024)
    float* out = (float*)d_out;

    char* ws = (char*)d_ws;
    // Liveness-overlapped layout (peak 73.25 MiB):
    float*          xr    = (float*)(ws);                      // [0,32M) fp32
    float*          xs    = (float*)(ws + 33554432);           // [32M,48M) fp32
    unsigned short* wInT  = (unsigned short*)(ws + 33554432);  // 8M, dead before conv
    float*          delta = (float*)(ws + 50331648);           // [48M,64M)
    unsigned short* yb    = (unsigned short*)(ws + 50331648);  // 8M, after scan
    unsigned short* wOutT = (unsigned short*)(ws + 58720256);  // 4M, after scan
    float*          xp    = (float*)(ws + 67108864);           // 1.25M
    unsigned short* hb    = (unsigned short*)(ws + 68419584);  // 4M (LN..in_proj)
    float*          Pbuf  = (float*)(ws + 68419584);           // 4M (scan, reuses hb)
    float*          Sbuf  = (float*)(ws + 72613888);           // 4M

    // 1. LayerNorm -> bf16
    ln_bf16<<<MROWS, 256, 0, stream>>>(x, norm_w, norm_b, hb);

    // 2. cast+transpose in_proj_w (1024x4096) -> wInT (4096x1024 bf16)
    cast_transpose<<<dim3(4096 / 64, 1024 / 64), 256, 0, stream>>>(
        in_proj_w, wInT, DM, 2 * DI);

    // 3. in_proj MFMA: (2048x1024)@(1024x4096) -> xr fp32
    gemm_bf16<128, 128, 0><<<dim3(4096 / 128, MROWS / 128), 256, 0, stream>>>(
        hb, wInT, xr, MROWS, 2 * DI, DM, nullptr);

    // 4. conv + silu -> xs
    conv_silu<<<(BSZ * LLEN * DI) / 256, 256, 0, stream>>>(xr, conv_w, conv_b, xs);

    // 5. x_proj fp32: (2048x2048)@(2048x160) -> xp
    gemm_f32<0><<<dim3((NXP + 63) / 64, MROWS / 64), 256, 0, stream>>>(
        xs, DI, x_proj_w, NXP, xp, NXP, MROWS, NXP, DI, nullptr);

    // 6. dt_proj fp32 + softplus -> delta
    gemm_f32<1><<<dim3(DI / 64, MROWS / 64), 256, 0, stream>>>(
        xp, NXP, dt_proj_w, DI, delta, DI, MROWS, DI, DTR, dt_proj_b);

    // 7-9. chunked selective scan
    scan_ps<<<BSZ * NCH * (DI / 256), 256, 0, stream>>>(
        delta, xs, xp, A_log, Pbuf, Sbuf);
    scan_fix<<<(BSZ * DI * DS) / 256, 256, 0, stream>>>(Pbuf, Sbuf);
    scan_y<<<BSZ * NCH * (DI / 256), 256, 0, stream>>>(
        delta, xs, xp, xr, A_log, D_param, Pbuf);

    // 10. cast y -> bf16
    cast_bf16<<<(MROWS * DI / 4) / 256, 256, 0, stream>>>(xs, yb, MROWS * DI);

    // 11. cast+transpose out_proj_w (2048x1024) -> wOutT (1024x2048 bf16)
    cast_transpose<<<dim3(1024 / 64, 2048 / 64), 256, 0, stream>>>(
        out_proj_w, wOutT, DI, DM);

    // 12. out_proj MFMA + residual: (2048x2048)@(2048x1024) + x -> out
    gemm_bf16<128, 64, 2><<<dim3(1024 / 64, MROWS / 128), 256, 0, stream>>>(
        yb, wOutT, out, MROWS, DM, DI, x);
}

// Round 4
// 252.521 us; speedup vs baseline: 3.4039x; 1.4299x over previous
//
#include <hip/hip_runtime.h>
#include <hip/hip_bf16.h>
#include <math.h>

// Problem constants
#define BSZ     2
#define LLEN    1024
#define DM      1024
#define DI      2048
#define DS      16
#define DTR     128
#define NXP     160          // DTR + 2*DS
#define MROWS   (BSZ*LLEN)   // 2048
#define NCH     16           // scan chunks
#define CHL     (LLEN/NCH)   // 64 steps per chunk

typedef short  bf16x8 __attribute__((ext_vector_type(8)));   // 8 bf16 (4 VGPRs)
typedef float  f32x4  __attribute__((ext_vector_type(4)));

__device__ __forceinline__ unsigned short f2bf(float f) {
    unsigned int u = __float_as_uint(f);
    return (unsigned short)((u + 0x7FFFu + ((u >> 16) & 1u)) >> 16);   // RNE
}

// ---------------------------------------------------------------------------
// LayerNorm -> bf16 (2048 rows of 1024)
// ---------------------------------------------------------------------------
__global__ __launch_bounds__(256) void ln_bf16(
    const float* __restrict__ x, const float* __restrict__ w,
    const float* __restrict__ b, unsigned short* __restrict__ hb)
{
    const int r = blockIdx.x;
    const int tid = threadIdx.x;
    const float4 v = ((const float4*)(x + (size_t)r * DM))[tid];
    float s  = v.x + v.y + v.z + v.w;
    float q  = v.x*v.x + v.y*v.y + v.z*v.z + v.w*v.w;
    #pragma unroll
    for (int o = 32; o > 0; o >>= 1) {
        s += __shfl_down(s, o);
        q += __shfl_down(q, o);
    }
    __shared__ float ss[4], sq[4];
    if ((tid & 63) == 0) { ss[tid >> 6] = s; sq[tid >> 6] = q; }
    __syncthreads();
    s = ss[0] + ss[1] + ss[2] + ss[3];
    q = sq[0] + sq[1] + sq[2] + sq[3];
    const float mu  = s * (1.0f / DM);
    const float var = q * (1.0f / DM) - mu * mu;
    const float rs  = rsqrtf(var + 1e-5f);
    const float4 wv = ((const float4*)w)[tid];
    const float4 bv = ((const float4*)b)[tid];
    ushort4 ob;
    ob.x = f2bf((v.x - mu) * rs * wv.x + bv.x);
    ob.y = f2bf((v.y - mu) * rs * wv.y + bv.y);
    ob.z = f2bf((v.z - mu) * rs * wv.z + bv.z);
    ob.w = f2bf((v.w - mu) * rs * wv.w + bv.w);
    *(ushort4*)&hb[(size_t)r * DM + (tid << 2)] = ob;
}

// ---------------------------------------------------------------------------
// guarded cast+transpose: fp32 src[K][N] -> bf16 dst[N][K]
// ---------------------------------------------------------------------------
__global__ __launch_bounds__(256) void cast_transpose_g(
    const float* __restrict__ src, unsigned short* __restrict__ dst,
    int K, int N)
{
    __shared__ unsigned short t[64][68];
    const int tid = threadIdx.x;
    const int k0 = blockIdx.y * 64, n0 = blockIdx.x * 64;
    #pragma unroll
    for (int q = 0; q < 4; ++q) {
        int idx = q * 256 + tid;
        int r = idx >> 4, c = (idx & 15) * 4;
        if (k0 + r < K) {
            #pragma unroll
            for (int e = 0; e < 4; ++e)
                if (n0 + c + e < N)
                    t[r][c + e] = f2bf(src[(size_t)(k0 + r) * N + n0 + c + e]);
        }
    }
    __syncthreads();
    #pragma unroll
    for (int q = 0; q < 4; ++q) {
        int idx = q * 256 + tid;
        int r = idx >> 4, c = (idx & 15) * 4;    // dst row n0+r, cols k0+c..
        if (n0 + r < N) {
            #pragma unroll
            for (int e = 0; e < 4; ++e)
                if (k0 + c + e < K)
                    dst[(size_t)(n0 + r) * K + k0 + c + e] = t[c + e][r];
        }
    }
}

// ---------------------------------------------------------------------------
// cast fp32 -> bf16 flat
// ---------------------------------------------------------------------------
__global__ __launch_bounds__(256) void cast_bf16(
    const float* __restrict__ src, unsigned short* __restrict__ dst, int n)
{
    int i = (blockIdx.x * 256 + threadIdx.x) * 4;
    if (i < n) {
        float4 v = *(const float4*)&src[i];
        ushort4 o = { f2bf(v.x), f2bf(v.y), f2bf(v.z), f2bf(v.w) };
        *(ushort4*)&dst[i] = o;
    }
}

// ---------------------------------------------------------------------------
// bf16 MFMA GEMM: C[M,N](fp32) = A[M,K](bf16) @ Bt[N,K](bf16)^T
// BK=64, 256 threads = 4 waves (2x2), 16x16x32 MFMA.
// Split-K via blockIdx.z (kpb = K per z-slice); partial written to C + z*M*N.
// EPI: 0 none, 1 softplus(acc + bias[col]), 2 + resid[row*N+col]
// ---------------------------------------------------------------------------
template<int BM, int BN, int EPI>
__global__ __launch_bounds__(256) void gemm_bf16(
    const unsigned short* __restrict__ A,
    const unsigned short* __restrict__ Bt,
    float* __restrict__ C, int M, int N, int K, int kpb,
    const float* __restrict__ bias,
    const float* __restrict__ resid)
{
    constexpr int LDT = 72;
    __shared__ unsigned short As[BM][LDT];
    __shared__ unsigned short Bs[BN][LDT];
    const int tid  = threadIdx.x;
    const int m0   = blockIdx.y * BM;
    const int n0   = blockIdx.x * BN;
    const int kbeg = blockIdx.z * kpb;
    const int kend = kbeg + kpb;
    float* Cw = C + (size_t)blockIdx.z * M * N;
    const int wave = tid >> 6;
    const int lane = tid & 63;
    const int wr   = (wave >> 1) * (BM / 2);
    const int wc   = (wave & 1) * (BN / 2);
    constexpr int FM = BM / 32;
    constexpr int FN = BN / 32;
    const int l15 = lane & 15;
    const int kg  = lane >> 4;

    f32x4 acc[FM][FN] = {};

    for (int kt = kbeg; kt < kend; kt += 64) {
        __syncthreads();
        #pragma unroll
        for (int q = 0; q < BM / 32; ++q) {
            int idx = q * 256 + tid;
            int r = idx >> 3, c = (idx & 7) * 8;
            *(uint4*)&As[r][c] = *(const uint4*)&A[(size_t)(m0 + r) * K + kt + c];
        }
        #pragma unroll
        for (int q = 0; q < BN / 32; ++q) {
            int idx = q * 256 + tid;
            int r = idx >> 3, c = (idx & 7) * 8;
            *(uint4*)&Bs[r][c] = *(const uint4*)&Bt[(size_t)(n0 + r) * K + kt + c];
        }
        __syncthreads();
        #pragma unroll
        for (int ks = 0; ks < 2; ++ks) {
            bf16x8 af[FM], bfr[FN];
            #pragma unroll
            for (int i = 0; i < FM; ++i)
                af[i] = *(const bf16x8*)&As[wr + i * 16 + l15][ks * 32 + kg * 8];
            #pragma unroll
            for (int j = 0; j < FN; ++j)
                bfr[j] = *(const bf16x8*)&Bs[wc + j * 16 + l15][ks * 32 + kg * 8];
            #pragma unroll
            for (int i = 0; i < FM; ++i)
                #pragma unroll
                for (int j = 0; j < FN; ++j)
                    acc[i][j] = __builtin_amdgcn_mfma_f32_16x16x32_bf16(
                        af[i], bfr[j], acc[i][j], 0, 0, 0);
        }
    }
    // C/D layout: col = lane&15, row = (lane>>4)*4 + reg   [m89-verified]
    #pragma unroll
    for (int i = 0; i < FM; ++i) {
        #pragma unroll
        for (int j = 0; j < FN; ++j) {
            const int row = m0 + wr + i * 16 + kg * 4;
            const int col = n0 + wc + j * 16 + l15;
            #pragma unroll
            for (int r = 0; r < 4; ++r) {
                float v = acc[i][j][r];
                if (EPI == 1) {
                    float t = v + bias[col];
                    v = (t > 20.f) ? t : log1pf(__expf(t));
                } else if (EPI == 2) {
                    v += resid[(size_t)(row + r) * N + col];
                }
                Cw[(size_t)(row + r) * N + col] = v;
            }
        }
    }
}

// ---------------------------------------------------------------------------
// x_proj split-K reduce: sum 4 partials; write xp fp32 + dr bf16 (cols<128)
// ---------------------------------------------------------------------------
__global__ __launch_bounds__(256) void xproj_reduce(
    const float* __restrict__ P4, float* __restrict__ xp,
    unsigned short* __restrict__ drb)
{
    const int idx = blockIdx.x * 256 + threadIdx.x;   // < 2048*160
    float s = 0.f;
    #pragma unroll
    for (int j = 0; j < 4; ++j)
        s += P4[(size_t)j * (MROWS * NXP) + idx];
    xp[idx] = s;
    const int row = idx / NXP, col = idx - row * NXP;
    if (col < DTR) drb[(size_t)row * DTR + col] = f2bf(s);
}

// ---------------------------------------------------------------------------
// causal depthwise conv (K=4) + SiLU; writes fp32 xs and bf16 xsb
// ---------------------------------------------------------------------------
__global__ __launch_bounds__(256) void conv_silu(
    const float* __restrict__ xr, const float* __restrict__ cw,
    const float* __restrict__ cb, float* __restrict__ xs,
    unsigned short* __restrict__ xsb)
{
    const int idx = blockIdx.x * 256 + threadIdx.x;
    const int d = idx & (DI - 1);
    const int t = (idx >> 11) & (LLEN - 1);
    const int b = idx >> 21;
    const float4 wv = ((const float4*)cw)[d];
    const float w[4] = {wv.x, wv.y, wv.z, wv.w};
    float acc = cb[d];
    #pragma unroll
    for (int k = 0; k < 4; ++k) {
        const int tt = t + k - 3;
        if (tt >= 0)
            acc = fmaf(w[k], xr[((size_t)(b * LLEN + tt) << 12) + d], acc);
    }
    const float sig = 1.f / (1.f + __expf(-acc));
    const float v = acc * sig;
    xs[idx] = v;
    xsb[idx] = f2bf(v);
}

// ---------------------------------------------------------------------------
// Scan pass A: per (b,d,chunk): P = prod dA, S = chunk-local final h
// ---------------------------------------------------------------------------
__global__ __launch_bounds__(256) void scan_ps(
    const float* __restrict__ delta, const float* __restrict__ xs,
    const float* __restrict__ xp, const float* __restrict__ A_log,
    float* __restrict__ P, float* __restrict__ S)
{
    const int blk  = blockIdx.x;
    const int dgrp = blk & 7;
    const int j    = (blk >> 3) & (NCH - 1);
    const int b    = blk >> 7;
    const int d    = dgrp * 256 + threadIdx.x;
    float aL[DS], h[DS], Pp[DS];
    #pragma unroll
    for (int n = 0; n < DS; ++n) {
        aL[n] = -__expf(A_log[d * DS + n]) * 1.44269504088896f;
        h[n] = 0.f; Pp[n] = 1.f;
    }
    const int t0 = j * CHL;
    for (int t = t0; t < t0 + CHL; ++t) {
        const size_t row = (size_t)(b * LLEN + t);
        const float dlt = delta[row * DI + d];
        const float du  = dlt * xs[row * DI + d];
        const float* Bp = &xp[row * NXP + DTR];
        #pragma unroll
        for (int n = 0; n < DS; ++n) {
            const float dA = exp2f(dlt * aL[n]);
            h[n] = fmaf(dA, h[n], du * Bp[n]);
            Pp[n] *= dA;
        }
    }
    float* Po = &P[(((size_t)j * BSZ + b) * DI + d) * DS];
    float* So = &S[(((size_t)j * BSZ + b) * DI + d) * DS];
    #pragma unroll
    for (int n = 0; n < DS; ++n) { Po[n] = Pp[n]; So[n] = h[n]; }
}

// ---------------------------------------------------------------------------
// Scan pass B: sequential inter-chunk fix-up; writes H0 over P in-place.
// ---------------------------------------------------------------------------
__global__ __launch_bounds__(256) void scan_fix(
    float* __restrict__ P, const float* __restrict__ S)
{
    const int c = blockIdx.x * 256 + threadIdx.x;   // (b,d,n) chain
    const int stride = BSZ * DI * DS;
    float h = 0.f;
    #pragma unroll
    for (int j = 0; j < NCH; ++j) {
        const float Pj = P[(size_t)j * stride + c];
        const float Sj = S[(size_t)j * stride + c];
        P[(size_t)j * stride + c] = h;              // H0 for chunk j
        h = fmaf(Pj, h, Sj);
    }
}

// ---------------------------------------------------------------------------
// Scan pass C: re-run chunk with h0; y = (sum h*C + D*u) * silu(res), in xs
// ---------------------------------------------------------------------------
__global__ __launch_bounds__(256) void scan_y(
    const float* __restrict__ delta, float* __restrict__ xs,
    const float* __restrict__ xp, const float* __restrict__ xr,
    const float* __restrict__ A_log, const float* __restrict__ Dp,
    const float* __restrict__ H0)
{
    const int blk  = blockIdx.x;
    const int dgrp = blk & 7;
    const int j    = (blk >> 3) & (NCH - 1);
    const int b    = blk >> 7;
    const int d    = dgrp * 256 + threadIdx.x;
    float aL[DS], h[DS];
    const float* H = &H0[(((size_t)j * BSZ + b) * DI + d) * DS];
    #pragma unroll
    for (int n = 0; n < DS; ++n) {
        aL[n] = -__expf(A_log[d * DS + n]) * 1.44269504088896f;
        h[n] = H[n];
    }
    const float Dd = Dp[d];
    const int t0 = j * CHL;
    for (int t = t0; t < t0 + CHL; ++t) {
        const size_t row = (size_t)(b * LLEN + t);
        const float dlt = delta[row * DI + d];
        const float u   = xs[row * DI + d];
        const float du  = dlt * u;
        const float* Bp = &xp[row * NXP + DTR];
        const float* Cp = Bp + DS;
        float y = Dd * u;
        #pragma unroll
        for (int n = 0; n < DS; ++n) {
            const float dA = exp2f(dlt * aL[n]);
            h[n] = fmaf(dA, h[n], du * Bp[n]);
            y = fmaf(h[n], Cp[n], y);
        }
        const float r = xr[(row << 12) + DI + d];
        xs[row * DI + d] = y * (r / (1.f + __expf(-r)));
    }
}

// ---------------------------------------------------------------------------
extern "C" void kernel_launch(void* const* d_in, const int* in_sizes, int n_in,
                              void* d_out, int out_size, void* d_ws, size_t ws_size,
                              hipStream_t stream)
{
    (void)in_sizes; (void)n_in; (void)out_size; (void)ws_size;
    const float* x         = (const float*)d_in[0];
    const float* norm_w    = (const float*)d_in[1];
    const float* norm_b    = (const float*)d_in[2];
    const float* in_proj_w = (const float*)d_in[3];   // (1024, 4096)
    const float* conv_w    = (const float*)d_in[4];
    const float* conv_b    = (const float*)d_in[5];
    const float* x_proj_w  = (const float*)d_in[6];   // (2048, 160)
    const float* dt_proj_w = (const float*)d_in[7];   // (128, 2048)
    const float* dt_proj_b = (const float*)d_in[8];
    const float* A_log     = (const float*)d_in[9];
    const float* D_param   = (const float*)d_in[10];
    const float* out_proj_w= (const float*)d_in[11];  // (2048, 1024)
    float* out = (float*)d_out;

    // Workspace overlays (peak 76,808,192 B — proven). Lifetimes disjoint
    // per-dispatch; see comments. d<N> = dispatch index.
    char* ws = (char*)d_ws;
    float*          xr    = (float*)(ws);                      // 32M  d3..d9
    float*          xs    = (float*)(ws + 33554432);           // 16M  d4..d10
    unsigned short* wInT  = (unsigned short*)(ws + 33554432);  // 8M   d2a..d3
    float*          delta = (float*)(ws + 50331648);           // 16M  d6..d9
    float*          P4    = (float*)(ws + 50331648);           // 5.25M d5..d5r
    unsigned short* xsb   = (unsigned short*)(ws + 55574528);  // 8M   d4..d5
    unsigned short* wOutT = (unsigned short*)(ws + 58720256);  // 4M   d11..d12
    unsigned short* yb    = (unsigned short*)(ws + 50331648);  // 8M   d10..d12
    float*          xp    = (float*)(ws + 67108864);           // 1.25M d5r..d9
    unsigned short* hb    = (unsigned short*)(ws + 68419584);  // 4M   d1..d3
    unsigned short* drb   = (unsigned short*)(ws + 68419584);  // 512K d5r..d6
    float*          Pbuf  = (float*)(ws + 68419584);           // 4M   d7..d9
    float*          Sbuf  = (float*)(ws + 72613888);           // 4M   d7..d8
    unsigned short* wXT   = (unsigned short*)(ws + 72613888);  // 640K d2b..d5
    unsigned short* dtwT  = (unsigned short*)(ws + 73269248);  // 512K d2c..d6

    // d1. LayerNorm -> bf16
    ln_bf16<<<MROWS, 256, 0, stream>>>(x, norm_w, norm_b, hb);

    // d2. weight casts/transposes
    cast_transpose_g<<<dim3(64, 16), 256, 0, stream>>>(in_proj_w, wInT, DM, 2 * DI);
    cast_transpose_g<<<dim3(3, 32), 256, 0, stream>>>(x_proj_w, wXT, DI, NXP);
    cast_transpose_g<<<dim3(32, 2), 256, 0, stream>>>(dt_proj_w, dtwT, DTR, DI);

    // d3. in_proj MFMA: (2048x1024)@(1024x4096) -> xr fp32
    gemm_bf16<128, 128, 0><<<dim3(32, 16, 1), 256, 0, stream>>>(
        hb, wInT, xr, MROWS, 2 * DI, DM, DM, nullptr, nullptr);

    // d4. conv + silu -> xs fp32, xsb bf16
    conv_silu<<<(BSZ * LLEN * DI) / 256, 256, 0, stream>>>(xr, conv_w, conv_b, xs, xsb);

    // d5. x_proj MFMA split-K=4: (2048x2048)@(2048x160) -> P4 partials
    gemm_bf16<128, 32, 0><<<dim3(5, 16, 4), 256, 0, stream>>>(
        xsb, wXT, P4, MROWS, NXP, DI, DI / 4, nullptr, nullptr);
    // d5r. reduce -> xp fp32, drb bf16
    xproj_reduce<<<(MROWS * NXP) / 256, 256, 0, stream>>>(P4, xp, drb);

    // d6. dt_proj MFMA + softplus: (2048x128)@(128x2048) -> delta fp32
    gemm_bf16<128, 128, 1><<<dim3(16, 16, 1), 256, 0, stream>>>(
        drb, dtwT, delta, MROWS, DI, DTR, DTR, dt_proj_b, nullptr);

    // d7-d9. chunked selective scan
    scan_ps<<<BSZ * NCH * (DI / 256), 256, 0, stream>>>(
        delta, xs, xp, A_log, Pbuf, Sbuf);
    scan_fix<<<(BSZ * DI * DS) / 256, 256, 0, stream>>>(Pbuf, Sbuf);
    scan_y<<<BSZ * NCH * (DI / 256), 256, 0, stream>>>(
        delta, xs, xp, xr, A_log, D_param, Pbuf);

    // d10. cast y -> bf16
    cast_bf16<<<(MROWS * DI / 4) / 256, 256, 0, stream>>>(xs, yb, MROWS * DI);

    // d11. cast+transpose out_proj_w (2048x1024) -> wOutT (1024x2048 bf16)
    cast_transpose_g<<<dim3(16, 32), 256, 0, stream>>>(out_proj_w, wOutT, DI, DM);

    // d12. out_proj MFMA + residual: (2048x2048)@(2048x1024) + x -> out
    gemm_bf16<128, 64, 2><<<dim3(16, 16, 1), 256, 0, stream>>>(
        yb, wOutT, out, MROWS, DM, DI, DI, nullptr, x);
}

// Round 5
// 220.690 us; speedup vs baseline: 3.8949x; 1.1442x over previous
//
#include <hip/hip_runtime.h>
#include <hip/hip_bf16.h>
#include <math.h>

// Problem constants
#define BSZ     2
#define LLEN    1024
#define DM      1024
#define DI      2048
#define DS      16
#define DTR     128
#define NXP     160          // DTR + 2*DS
#define MROWS   (BSZ*LLEN)   // 2048
#define NCH     32           // scan chunks
#define CHL     (LLEN/NCH)   // 32 steps per chunk

typedef short  bf16x8 __attribute__((ext_vector_type(8)));   // 8 bf16 (4 VGPRs)
typedef float  f32x4  __attribute__((ext_vector_type(4)));

__device__ __forceinline__ unsigned short f2bf(float f) {
    unsigned int u = __float_as_uint(f);
    return (unsigned short)((u + 0x7FFFu + ((u >> 16) & 1u)) >> 16);   // RNE
}

// ---------------------------------------------------------------------------
// LayerNorm -> bf16 (2048 rows of 1024)
// ---------------------------------------------------------------------------
__global__ __launch_bounds__(256) void ln_bf16(
    const float* __restrict__ x, const float* __restrict__ w,
    const float* __restrict__ b, unsigned short* __restrict__ hb)
{
    const int r = blockIdx.x;
    const int tid = threadIdx.x;
    const float4 v = ((const float4*)(x + (size_t)r * DM))[tid];
    float s  = v.x + v.y + v.z + v.w;
    float q  = v.x*v.x + v.y*v.y + v.z*v.z + v.w*v.w;
    #pragma unroll
    for (int o = 32; o > 0; o >>= 1) {
        s += __shfl_down(s, o);
        q += __shfl_down(q, o);
    }
    __shared__ float ss[4], sq[4];
    if ((tid & 63) == 0) { ss[tid >> 6] = s; sq[tid >> 6] = q; }
    __syncthreads();
    s = ss[0] + ss[1] + ss[2] + ss[3];
    q = sq[0] + sq[1] + sq[2] + sq[3];
    const float mu  = s * (1.0f / DM);
    const float var = q * (1.0f / DM) - mu * mu;
    const float rs  = rsqrtf(var + 1e-5f);
    const float4 wv = ((const float4*)w)[tid];
    const float4 bv = ((const float4*)b)[tid];
    ushort4 ob;
    ob.x = f2bf((v.x - mu) * rs * wv.x + bv.x);
    ob.y = f2bf((v.y - mu) * rs * wv.y + bv.y);
    ob.z = f2bf((v.z - mu) * rs * wv.z + bv.z);
    ob.w = f2bf((v.w - mu) * rs * wv.w + bv.w);
    *(ushort4*)&hb[(size_t)r * DM + (tid << 2)] = ob;
}

// ---------------------------------------------------------------------------
// guarded cast+transpose: fp32 src[K][N] -> bf16 dst[N][K]
// ---------------------------------------------------------------------------
__global__ __launch_bounds__(256) void cast_transpose_g(
    const float* __restrict__ src, unsigned short* __restrict__ dst,
    int K, int N)
{
    __shared__ unsigned short t[64][68];
    const int tid = threadIdx.x;
    const int k0 = blockIdx.y * 64, n0 = blockIdx.x * 64;
    #pragma unroll
    for (int q = 0; q < 4; ++q) {
        int idx = q * 256 + tid;
        int r = idx >> 4, c = (idx & 15) * 4;
        if (k0 + r < K) {
            #pragma unroll
            for (int e = 0; e < 4; ++e)
                if (n0 + c + e < N)
                    t[r][c + e] = f2bf(src[(size_t)(k0 + r) * N + n0 + c + e]);
        }
    }
    __syncthreads();
    #pragma unroll
    for (int q = 0; q < 4; ++q) {
        int idx = q * 256 + tid;
        int r = idx >> 4, c = (idx & 15) * 4;
        if (n0 + r < N) {
            #pragma unroll
            for (int e = 0; e < 4; ++e)
                if (k0 + c + e < K)
                    dst[(size_t)(n0 + r) * K + k0 + c + e] = t[c + e][r];
        }
    }
}

// ---------------------------------------------------------------------------
// bf16 MFMA GEMM: C[M,N](fp32) = A[M,K](bf16) @ Bt[N,K](bf16)^T
// BK=64, 256 threads = 4 waves (2x2), 16x16x32 MFMA.
// Split-K via blockIdx.z (kpb); partial -> C + z*M*N.
// EPI: 0 none, 1 softplus(acc + bias[col]), 2 + resid[row*N+col]
// ---------------------------------------------------------------------------
template<int BM, int BN, int EPI>
__global__ __launch_bounds__(256) void gemm_bf16(
    const unsigned short* __restrict__ A,
    const unsigned short* __restrict__ Bt,
    float* __restrict__ C, int M, int N, int K, int kpb,
    const float* __restrict__ bias,
    const float* __restrict__ resid)
{
    constexpr int LDT = 72;
    __shared__ unsigned short As[BM][LDT];
    __shared__ unsigned short Bs[BN][LDT];
    const int tid  = threadIdx.x;
    const int m0   = blockIdx.y * BM;
    const int n0   = blockIdx.x * BN;
    const int kbeg = blockIdx.z * kpb;
    const int kend = kbeg + kpb;
    float* Cw = C + (size_t)blockIdx.z * M * N;
    const int wave = tid >> 6;
    const int lane = tid & 63;
    const int wr   = (wave >> 1) * (BM / 2);
    const int wc   = (wave & 1) * (BN / 2);
    constexpr int FM = BM / 32;
    constexpr int FN = BN / 32;
    const int l15 = lane & 15;
    const int kg  = lane >> 4;

    f32x4 acc[FM][FN] = {};

    for (int kt = kbeg; kt < kend; kt += 64) {
        __syncthreads();
        #pragma unroll
        for (int q = 0; q < BM / 32; ++q) {
            int idx = q * 256 + tid;
            int r = idx >> 3, c = (idx & 7) * 8;
            *(uint4*)&As[r][c] = *(const uint4*)&A[(size_t)(m0 + r) * K + kt + c];
        }
        #pragma unroll
        for (int q = 0; q < BN / 32; ++q) {
            int idx = q * 256 + tid;
            int r = idx >> 3, c = (idx & 7) * 8;
            *(uint4*)&Bs[r][c] = *(const uint4*)&Bt[(size_t)(n0 + r) * K + kt + c];
        }
        __syncthreads();
        #pragma unroll
        for (int ks = 0; ks < 2; ++ks) {
            bf16x8 af[FM], bfr[FN];
            #pragma unroll
            for (int i = 0; i < FM; ++i)
                af[i] = *(const bf16x8*)&As[wr + i * 16 + l15][ks * 32 + kg * 8];
            #pragma unroll
            for (int j = 0; j < FN; ++j)
                bfr[j] = *(const bf16x8*)&Bs[wc + j * 16 + l15][ks * 32 + kg * 8];
            #pragma unroll
            for (int i = 0; i < FM; ++i)
                #pragma unroll
                for (int j = 0; j < FN; ++j)
                    acc[i][j] = __builtin_amdgcn_mfma_f32_16x16x32_bf16(
                        af[i], bfr[j], acc[i][j], 0, 0, 0);
        }
    }
    // C/D layout: col = lane&15, row = (lane>>4)*4 + reg   [m89-verified]
    #pragma unroll
    for (int i = 0; i < FM; ++i) {
        #pragma unroll
        for (int j = 0; j < FN; ++j) {
            const int row = m0 + wr + i * 16 + kg * 4;
            const int col = n0 + wc + j * 16 + l15;
            #pragma unroll
            for (int r = 0; r < 4; ++r) {
                float v = acc[i][j][r];
                if (EPI == 1) {
                    float t = v + bias[col];
                    v = (t > 20.f) ? t : log1pf(__expf(t));
                } else if (EPI == 2) {
                    v += resid[(size_t)(row + r) * N + col];
                }
                Cw[(size_t)(row + r) * N + col] = v;
            }
        }
    }
}

// ---------------------------------------------------------------------------
// x_proj split-K reduce: sum 4 partials; write xp fp32 + dr bf16 (cols<128)
// ---------------------------------------------------------------------------
__global__ __launch_bounds__(256) void xproj_reduce(
    const float* __restrict__ P4, float* __restrict__ xp,
    unsigned short* __restrict__ drb)
{
    const int idx = blockIdx.x * 256 + threadIdx.x;   // < 2048*160
    float s = 0.f;
    #pragma unroll
    for (int j = 0; j < 4; ++j)
        s += P4[(size_t)j * (MROWS * NXP) + idx];
    xp[idx] = s;
    const int row = idx / NXP, col = idx - row * NXP;
    if (col < DTR) drb[(size_t)row * DTR + col] = f2bf(s);
}

// ---------------------------------------------------------------------------
// causal depthwise conv (K=4) + SiLU; writes xs fp32, xsb bf16, g=silu(res)
// ---------------------------------------------------------------------------
__global__ __launch_bounds__(256) void conv_silu(
    const float* __restrict__ xr, const float* __restrict__ cw,
    const float* __restrict__ cb, float* __restrict__ xs,
    unsigned short* __restrict__ xsb, float* __restrict__ g)
{
    const int idx = blockIdx.x * 256 + threadIdx.x;
    const int d = idx & (DI - 1);
    const int t = (idx >> 11) & (LLEN - 1);
    const int b = idx >> 21;
    const float4 wv = ((const float4*)cw)[d];
    const float w[4] = {wv.x, wv.y, wv.z, wv.w};
    float acc = cb[d];
    #pragma unroll
    for (int k = 0; k < 4; ++k) {
        const int tt = t + k - 3;
        if (tt >= 0)
            acc = fmaf(w[k], xr[((size_t)(b * LLEN + tt) << 12) + d], acc);
    }
    const float sig = 1.f / (1.f + __expf(-acc));
    const float v = acc * sig;
    xs[idx] = v;
    xsb[idx] = f2bf(v);
    // gate: silu of res half (cols 2048..4095 of xr)
    const float r = xr[((size_t)(b * LLEN + t) << 12) + DI + d];
    g[idx] = r / (1.f + __expf(-r));
}

// ---------------------------------------------------------------------------
// Scan pass A: per (b,d,chunk): S = chunk-local final h (16), sdlt = sum delta
// (full-chunk decay P[n] = exp2(aL[n]*sdlt) — reconstructed in pass B)
// ---------------------------------------------------------------------------
__global__ __launch_bounds__(256) void scan_ps(
    const float* __restrict__ delta, const float* __restrict__ xs,
    const float* __restrict__ xp, const float* __restrict__ A_log,
    float* __restrict__ S, float* __restrict__ sdlt)
{
    const int blk  = blockIdx.x;
    const int dgrp = blk & 7;
    const int j    = (blk >> 3) & (NCH - 1);
    const int b    = blk >> 8;
    const int d    = dgrp * 256 + threadIdx.x;
    float aL[DS], h[DS];
    #pragma unroll
    for (int n = 0; n < DS; ++n) {
        aL[n] = -__expf(A_log[d * DS + n]) * 1.44269504088896f;
        h[n] = 0.f;
    }
    float sd = 0.f;
    const int t0 = j * CHL;
    for (int t = t0; t < t0 + CHL; ++t) {
        const size_t row = (size_t)(b * LLEN + t);
        const float dlt = delta[row * DI + d];
        const float du  = dlt * xs[row * DI + d];
        sd += dlt;
        const float* Bp = &xp[row * NXP + DTR];
        #pragma unroll
        for (int n = 0; n < DS; ++n) {
            const float dA = exp2f(dlt * aL[n]);
            h[n] = fmaf(dA, h[n], du * Bp[n]);
        }
    }
    float* So = &S[(((size_t)j * BSZ + b) * DI + d) * DS];
    #pragma unroll
    for (int n = 0; n < DS; ++n) So[n] = h[n];
    sdlt[((size_t)j * BSZ + b) * DI + d] = sd;
}

// ---------------------------------------------------------------------------
// Scan pass B: sequential inter-chunk fix-up. Thread per (b,d,n).
// Reads S + sdlt, writes H0 (state entering chunk j) in-place over S.
// ---------------------------------------------------------------------------
__global__ __launch_bounds__(256) void scan_fix(
    float* __restrict__ S, const float* __restrict__ sdlt,
    const float* __restrict__ A_log)
{
    const int c = blockIdx.x * 256 + threadIdx.x;   // < 2*2048*16
    const int n = c & 15;
    const int d = (c >> 4) & (DI - 1);
    const int b = c >> 15;
    const float aL = -__expf(A_log[d * DS + n]) * 1.44269504088896f;
    float h = 0.f;
    #pragma unroll
    for (int j = 0; j < NCH; ++j) {
        const size_t base = ((size_t)j * BSZ + b) * DI + d;
        const float Pj = exp2f(aL * sdlt[base]);
        const float Sj = S[base * DS + n];
        S[base * DS + n] = h;                        // H0 for chunk j
        h = fmaf(Pj, h, Sj);
    }
}

// ---------------------------------------------------------------------------
// Scan pass C: re-run chunk with h0; y = (sum h*C + D*u) * g; write bf16 yb
// ---------------------------------------------------------------------------
__global__ __launch_bounds__(256) void scan_y(
    const float* __restrict__ delta, const float* __restrict__ xs,
    const float* __restrict__ xp, const float* __restrict__ g,
    const float* __restrict__ A_log, const float* __restrict__ Dp,
    const float* __restrict__ H0, unsigned short* __restrict__ yb)
{
    const int blk  = blockIdx.x;
    const int dgrp = blk & 7;
    const int j    = (blk >> 3) & (NCH - 1);
    const int b    = blk >> 8;
    const int d    = dgrp * 256 + threadIdx.x;
    float aL[DS], h[DS];
    const float* H = &H0[(((size_t)j * BSZ + b) * DI + d) * DS];
    #pragma unroll
    for (int n = 0; n < DS; ++n) {
        aL[n] = -__expf(A_log[d * DS + n]) * 1.44269504088896f;
        h[n] = H[n];
    }
    const float Dd = Dp[d];
    const int t0 = j * CHL;
    for (int t = t0; t < t0 + CHL; ++t) {
        const size_t row = (size_t)(b * LLEN + t);
        const float dlt = delta[row * DI + d];
        const float u   = xs[row * DI + d];
        const float du  = dlt * u;
        const float* Bp = &xp[row * NXP + DTR];
        const float* Cp = Bp + DS;
        float y = Dd * u;
        #pragma unroll
        for (int n = 0; n < DS; ++n) {
            const float dA = exp2f(dlt * aL[n]);
            h[n] = fmaf(dA, h[n], du * Bp[n]);
            y = fmaf(h[n], Cp[n], y);
        }
        yb[row * DI + d] = f2bf(y * g[row * DI + d]);
    }
}

// ---------------------------------------------------------------------------
extern "C" void kernel_launch(void* const* d_in, const int* in_sizes, int n_in,
                              void* d_out, int out_size, void* d_ws, size_t ws_size,
                              hipStream_t stream)
{
    (void)in_sizes; (void)n_in; (void)out_size; (void)ws_size;
    const float* x         = (const float*)d_in[0];
    const float* norm_w    = (const float*)d_in[1];
    const float* norm_b    = (const float*)d_in[2];
    const float* in_proj_w = (const float*)d_in[3];   // (1024, 4096)
    const float* conv_w    = (const float*)d_in[4];
    const float* conv_b    = (const float*)d_in[5];
    const float* x_proj_w  = (const float*)d_in[6];   // (2048, 160)
    const float* dt_proj_w = (const float*)d_in[7];   // (128, 2048)
    const float* dt_proj_b = (const float*)d_in[8];
    const float* A_log     = (const float*)d_in[9];
    const float* D_param   = (const float*)d_in[10];
    const float* out_proj_w= (const float*)d_in[11];  // (2048, 1024)
    float* out = (float*)d_out;

    // Workspace overlays (peak 76,677,120 B ≤ proven 76,808,192).
    // Lifetimes (d<N> = dispatch index) verified disjoint per-dispatch:
    char* ws = (char*)d_ws;
    float*          xr    = (float*)(ws);                      // 32M  d3..d4
    float*          P4    = (float*)(ws);                      // 5.25M d5..d5r
    float*          delta = (float*)(ws);                      // 16M  d6..d9
    float*          Sbuf  = (float*)(ws + 16777216);           // 8M   d7..d9
    float*          xp    = (float*)(ws + 25165824);           // 1.25M d5r..d9
    unsigned short* drb   = (unsigned short*)(ws + 27262976);  // 512K d5r..d6
    float*          sdlt  = (float*)(ws + 27787264);           // 512K d7..d8
    float*          xs    = (float*)(ws + 33554432);           // 16M  d4..d9
    float*          g     = (float*)(ws + 50331648);           // 16M  d4..d9
    unsigned short* wInT  = (unsigned short*)(ws + 50331648);  // 8M   d2..d3
    unsigned short* hb    = (unsigned short*)(ws + 58720256);  // 4M   d1..d3
    unsigned short* wOutT = (unsigned short*)(ws + 58720256);  // 4M   d11..d12
    unsigned short* xsb   = (unsigned short*)(ws + 67108864);  // 8M   d4..d5
    unsigned short* yb    = (unsigned short*)(ws + 67108864);  // 8M   d9..d12
    unsigned short* wXT   = (unsigned short*)(ws + 75497472);  // 640K d2..d5
    unsigned short* dtwT  = (unsigned short*)(ws + 76152832);  // 512K d2..d6

    // d1. LayerNorm -> bf16
    ln_bf16<<<MROWS, 256, 0, stream>>>(x, norm_w, norm_b, hb);

    // d2. weight casts/transposes
    cast_transpose_g<<<dim3(64, 16), 256, 0, stream>>>(in_proj_w, wInT, DM, 2 * DI);
    cast_transpose_g<<<dim3(3, 32), 256, 0, stream>>>(x_proj_w, wXT, DI, NXP);
    cast_transpose_g<<<dim3(32, 2), 256, 0, stream>>>(dt_proj_w, dtwT, DTR, DI);

    // d3. in_proj MFMA: (2048x1024)@(1024x4096) -> xr fp32
    gemm_bf16<128, 128, 0><<<dim3(32, 16, 1), 256, 0, stream>>>(
        hb, wInT, xr, MROWS, 2 * DI, DM, DM, nullptr, nullptr);

    // d4. conv + silu -> xs fp32, xsb bf16, g = silu(res) fp32
    conv_silu<<<(BSZ * LLEN * DI) / 256, 256, 0, stream>>>(
        xr, conv_w, conv_b, xs, xsb, g);

    // d5. x_proj MFMA split-K=4 -> P4 partials
    gemm_bf16<128, 32, 0><<<dim3(5, 16, 4), 256, 0, stream>>>(
        xsb, wXT, P4, MROWS, NXP, DI, DI / 4, nullptr, nullptr);
    // d5r. reduce -> xp fp32, drb bf16
    xproj_reduce<<<(MROWS * NXP) / 256, 256, 0, stream>>>(P4, xp, drb);

    // d6. dt_proj MFMA + softplus -> delta fp32
    gemm_bf16<128, 128, 1><<<dim3(16, 16, 1), 256, 0, stream>>>(
        drb, dtwT, delta, MROWS, DI, DTR, DTR, dt_proj_b, nullptr);

    // d7-d9. chunked selective scan (NCH=32)
    scan_ps<<<BSZ * NCH * (DI / 256), 256, 0, stream>>>(
        delta, xs, xp, A_log, Sbuf, sdlt);
    scan_fix<<<(BSZ * DI * DS) / 256, 256, 0, stream>>>(Sbuf, sdlt, A_log);
    scan_y<<<BSZ * NCH * (DI / 256), 256, 0, stream>>>(
        delta, xs, xp, g, A_log, D_param, Sbuf, yb);

    // d11. cast+transpose out_proj_w -> wOutT (1024x2048 bf16)
    cast_transpose_g<<<dim3(16, 32), 256, 0, stream>>>(out_proj_w, wOutT, DI, DM);

    // d12. out_proj MFMA + residual -> out
    gemm_bf16<128, 64, 2><<<dim3(16, 16, 1), 256, 0, stream>>>(
        yb, wOutT, out, MROWS, DM, DI, DI, nullptr, x);
}